// Round 5
// baseline (36.067 us; speedup 1.0000x reference)
//
#include <hip/hip_runtime.h>
#include <hip/hip_fp16.h>

#define NH 6
#define NS 16
#define GN 97              // table nodes per axis
#define LIM 6.0f           // fast-path input bound
#define ORIG -6.08f        // grid origin
#define DLT 0.12666667f    // (2*6.08)/96
#define INV_D 7.8947368f   // 96/(2*6.08)
#define TAB_OFF 48.0f      // -ORIG*INV_D (u = p*INV_D + TAB_OFF)
#define BLK 1024
#define NBLK 512           // persistent: 2 blocks/CU on 256 CUs

struct P16 {
    const float *vW1,*vb1,*vW2,*vb2, *hW1,*hb1,*hW2,*hb2;
    const float *pvW1,*pvb1,*pvW2,*pvb2, *phW1,*phb1,*phW2,*phb2;
};

// tanh(x) = (e^{2x} - 1) / (e^{2x} + 1). Pre-activations bounded (|arg|<~10),
// no overflow guard needed; abs err ~1e-6 (table only needs ~1e-3).
__device__ __forceinline__ float fast_tanh(float x) {
    float e = __expf(2.0f * x);
    return (e - 1.0f) * __builtin_amdgcn_rcpf(e + 1.0f);
}

__device__ __forceinline__ float fcn6(float x,
        const float* __restrict__ W1, const float* __restrict__ b1,
        const float* __restrict__ W2, float b2v) {
    float acc = b2v;
    #pragma unroll
    for (int j = 0; j < NH; ++j)
        acc = fmaf(fast_tanh(fmaf(x, W1[j], b1[j])), W2[j], acc);
    return acc;
}

// Exact 54-shear map (table precompute and rare out-of-range path).
__device__ void full_map(float& p, float& q, const P16& w) {
    const float Hs = 0.1f;
    const float hi = Hs / NS;
    p = fmaf(fcn6(q, w.pvW1, w.pvb1, w.pvW2, w.pvb2[0]), -0.5f * Hs, p);
    q = fmaf(fcn6(p, w.phW1, w.phb1, w.phW2, w.phb2[0]),         Hs, q);
    p = fmaf(fcn6(q, w.pvW1, w.pvb1, w.pvW2, w.pvb2[0]), -0.5f * Hs, p);
    for (int s = 0; s < NS; ++s) {
        const float* a1 = w.vW1 + s * NH;
        const float* c1 = w.vb1 + s * NH;
        const float* a2 = w.vW2 + s * NH;
        const float* d1 = w.hW1 + s * NH;
        const float* e1 = w.hb1 + s * NH;
        const float* d2 = w.hW2 + s * NH;
        p = fmaf(fcn6(q, a1, c1, a2, w.vb2[s]), -0.5f * hi, p);
        q = fmaf(fcn6(p, d1, e1, d2, w.hb2[s]),         hi, q);
        p = fmaf(fcn6(q, a1, c1, a2, w.vb2[s]), -0.5f * hi, p);
    }
    p = fmaf(fcn6(q, w.pvW1, w.pvb1, w.pvW2, w.pvb2[0]),  0.5f * Hs, p);
    q = fmaf(fcn6(p, w.phW1, w.phb1, w.phW2, w.phb2[0]),        -Hs, q);
    p = fmaf(fcn6(q, w.pvW1, w.pvb1, w.pvW2, w.pvb2[0]),  0.5f * Hs, p);
}

// --- precompute: delta map (p'-p, q'-q) at 97x97 nodes, packed f16x2 ---
__global__ __launch_bounds__(256) void LHI_build_table(__half2* __restrict__ tg, P16 w) {
    const int n = blockIdx.x * blockDim.x + threadIdx.x;
    if (n >= GN * GN) return;
    const int i = n % GN, j = n / GN;
    const float p0 = fmaf((float)i, DLT, ORIG);
    const float q0 = fmaf((float)j, DLT, ORIG);
    float p = p0, q = q0;
    full_map(p, q, w);
    tg[n] = __floats2half2_rn(p - p0, q - q0);   // |delta| <= ~1, f16 err ~5e-4
}

__device__ __forceinline__ __half2 h2_from_u32(unsigned u) {
    union { unsigned u; __half2 h; } c; c.u = u; return c.h;
}

// One element through the bilinear-delta fast path (packed fp16 lerp).
__device__ __forceinline__ void lookup2(float& p, float& q,
        const uint2* __restrict__ tab, const P16& w) {
    if (fabsf(p) <= LIM && fabsf(q) <= LIM) {
        const float u  = fmaf(p, INV_D, TAB_OFF);   // in [0.63, 95.37]
        const float vv = fmaf(q, INV_D, TAB_OFF);
        const float fu = floorf(u), fv = floorf(vv);
        const int n00 = (int)fv * GN + (int)fu;
        const uint2 r0 = tab[n00];        // (c00, c10) : one ds_read_b64
        const uint2 r1 = tab[n00 + GN];   // (c01, c11)
        const __half2 du2 = __half2half2(__float2half_rn(u - fu));
        const __half2 dv2 = __half2half2(__float2half_rn(vv - fv));
        const __half2 c00 = h2_from_u32(r0.x), c10 = h2_from_u32(r0.y);
        const __half2 c01 = h2_from_u32(r1.x), c11 = h2_from_u32(r1.y);
        const __half2 m0 = __hfma2(du2, __hsub2(c10, c00), c00);
        const __half2 m1 = __hfma2(du2, __hsub2(c11, c01), c01);
        const __half2 m  = __hfma2(dv2, __hsub2(m1, m0), m0);
        const float2 d = __half22float2(m);
        p += d.x; q += d.y;
    } else {
        full_map(p, q, w);   // ~never: execz-skipped when no lane triggers
    }
}

// --- main: persistent grid-stride, float4 I/O, row-pair LDS table ---
__global__ __launch_bounds__(BLK) void LHI_81501299409121_kernel(
        const float4* __restrict__ x4, const __half2* __restrict__ tg,
        P16 w, float4* __restrict__ o4, int nquad, int do_tail,
        const float* __restrict__ x, float* __restrict__ out, int B) {
    __shared__ uint2 tab[GN * GN];   // entry n: (delta[n], delta[n+1]) 8B aligned
    const unsigned* tgu = (const unsigned*)tg;
    for (int n = threadIdx.x; n < GN * GN; n += BLK) {
        const int n1 = (n + 1 < GN * GN) ? n + 1 : n;
        tab[n] = make_uint2(tgu[n], tgu[n1]);
    }
    __syncthreads();

    const int tid0   = blockIdx.x * BLK + threadIdx.x;
    const int stride = NBLK * BLK;

    for (int i = tid0; i < nquad; i += stride) {
        float4 v = x4[i];
        lookup2(v.x, v.y, tab, w);
        lookup2(v.z, v.w, tab, w);
        o4[i] = v;
    }
    if (do_tail && tid0 == 0) {       // odd B: exact path for last element
        float p = x[2 * (B - 1)], q = x[2 * (B - 1) + 1];
        full_map(p, q, w);
        out[2 * (B - 1)] = p; out[2 * (B - 1) + 1] = q;
    }
}

// --- fallback if workspace can't hold the table ---
__global__ __launch_bounds__(256) void LHI_direct_kernel(
        const float* __restrict__ x, P16 w, float* __restrict__ out, int B) {
    const int idx = blockIdx.x * 256 + threadIdx.x;
    if (idx >= B) return;
    float2 v = ((const float2*)x)[idx];
    float p = v.x, q = v.y;
    full_map(p, q, w);
    ((float2*)out)[idx] = make_float2(p, q);
}

extern "C" void kernel_launch(void* const* d_in, const int* in_sizes, int n_in,
                              void* d_out, int out_size, void* d_ws, size_t ws_size,
                              hipStream_t stream) {
    const int B = in_sizes[0] / 2;   // x is [B,2]
    P16 w;
    w.vW1  = (const float*)d_in[1];  w.vb1  = (const float*)d_in[2];
    w.vW2  = (const float*)d_in[3];  w.vb2  = (const float*)d_in[4];
    w.hW1  = (const float*)d_in[5];  w.hb1  = (const float*)d_in[6];
    w.hW2  = (const float*)d_in[7];  w.hb2  = (const float*)d_in[8];
    w.pvW1 = (const float*)d_in[9];  w.pvb1 = (const float*)d_in[10];
    w.pvW2 = (const float*)d_in[11]; w.pvb2 = (const float*)d_in[12];
    w.phW1 = (const float*)d_in[13]; w.phb1 = (const float*)d_in[14];
    w.phW2 = (const float*)d_in[15]; w.phb2 = (const float*)d_in[16];
    const float* x = (const float*)d_in[0];
    float* out = (float*)d_out;

    const size_t tab_bytes = (size_t)GN * GN * sizeof(__half2);
    if (ws_size >= tab_bytes) {
        __half2* tg = (__half2*)d_ws;
        LHI_build_table<<<(GN * GN + 255) / 256, 256, 0, stream>>>(tg, w);
        const int nquad = B >> 1;
        const int do_tail = B & 1;
        LHI_81501299409121_kernel<<<NBLK, BLK, 0, stream>>>(
            (const float4*)x, tg, w, (float4*)out, nquad, do_tail, x, out, B);
    } else {
        LHI_direct_kernel<<<(B + 255) / 256, 256, 0, stream>>>(x, w, out, B);
    }
}

// Round 6
// 32.871 us; speedup vs baseline: 1.0972x; 1.0972x over previous
//
#include <hip/hip_runtime.h>
#include <hip/hip_fp16.h>

#define NH 6
#define NS 16
#define GN 97              // 2-D table nodes per axis
#define LIM 6.0f           // fast-path input bound
#define ORIG -6.08f        // 2-D grid origin
#define DLT 0.12666667f    // (2*6.08)/96
#define INV_D 7.8947368f   // 96/(2*6.08)
#define TAB_OFF 48.0f      // -ORIG*INV_D
#define BLK 1024
#define NBLK 512           // persistent main: 2 blocks/CU

// 1-D function tables: 34 distinct fcns (pv, ph, v[16], h[16]) x 512 pts over +-8
#define NF 34
#define N1 512
#define R1 8.0f
#define D1 0.031311154f    // 16/511
#define INV1 31.9375f      // 511/16
#define OFF1 255.5f        // R1*INV1

struct P16 {
    const float *vW1,*vb1,*vW2,*vb2, *hW1,*hb1,*hW2,*hb2;
    const float *pvW1,*pvb1,*pvW2,*pvb2, *phW1,*phb1,*phW2,*phb2;
};

// tanh(x) = (e^{2x}-1)/(e^{2x}+1); args bounded here, no overflow guard needed.
__device__ __forceinline__ float fast_tanh(float x) {
    float e = __expf(2.0f * x);
    return (e - 1.0f) * __builtin_amdgcn_rcpf(e + 1.0f);
}

__device__ __forceinline__ float fcn6(float x,
        const float* __restrict__ W1, const float* __restrict__ b1,
        const float* __restrict__ W2, float b2v) {
    float acc = b2v;
    #pragma unroll
    for (int j = 0; j < NH; ++j)
        acc = fmaf(fast_tanh(fmaf(x, W1[j], b1[j])), W2[j], acc);
    return acc;
}

// Exact 54-shear map (rare out-of-range path in main kernel).
__device__ void full_map(float& p, float& q, const P16& w) {
    const float Hs = 0.1f;
    const float hi = Hs / NS;
    p = fmaf(fcn6(q, w.pvW1, w.pvb1, w.pvW2, w.pvb2[0]), -0.5f * Hs, p);
    q = fmaf(fcn6(p, w.phW1, w.phb1, w.phW2, w.phb2[0]),         Hs, q);
    p = fmaf(fcn6(q, w.pvW1, w.pvb1, w.pvW2, w.pvb2[0]), -0.5f * Hs, p);
    for (int s = 0; s < NS; ++s) {
        const float* a1 = w.vW1 + s * NH;
        const float* c1 = w.vb1 + s * NH;
        const float* a2 = w.vW2 + s * NH;
        const float* d1 = w.hW1 + s * NH;
        const float* e1 = w.hb1 + s * NH;
        const float* d2 = w.hW2 + s * NH;
        p = fmaf(fcn6(q, a1, c1, a2, w.vb2[s]), -0.5f * hi, p);
        q = fmaf(fcn6(p, d1, e1, d2, w.hb2[s]),         hi, q);
        p = fmaf(fcn6(q, a1, c1, a2, w.vb2[s]), -0.5f * hi, p);
    }
    p = fmaf(fcn6(q, w.pvW1, w.pvb1, w.pvW2, w.pvb2[0]),  0.5f * Hs, p);
    q = fmaf(fcn6(p, w.phW1, w.phb1, w.phW2, w.phb2[0]),        -Hs, q);
    p = fmaf(fcn6(q, w.pvW1, w.pvb1, w.pvW2, w.pvb2[0]),  0.5f * Hs, p);
}

// --- K1: 34 independent 1-D fcn tables; chain depth = ONE fcn6 ---
__global__ __launch_bounds__(256) void LHI_build_1d(float* __restrict__ tg1, P16 w) {
    const int idx = blockIdx.x * 256 + threadIdx.x;   // 34*512 threads
    if (idx >= NF * N1) return;
    const int f = idx >> 9, i = idx & (N1 - 1);       // f uniform per block
    const float x = fmaf((float)i, D1, -R1);
    const float *W1, *b1v, *W2; float b2v;
    if (f == 0)       { W1 = w.pvW1; b1v = w.pvb1; W2 = w.pvW2; b2v = w.pvb2[0]; }
    else if (f == 1)  { W1 = w.phW1; b1v = w.phb1; W2 = w.phW2; b2v = w.phb2[0]; }
    else if (f < 18)  { int s = f - 2;  W1 = w.vW1 + s*NH; b1v = w.vb1 + s*NH; W2 = w.vW2 + s*NH; b2v = w.vb2[s]; }
    else              { int s = f - 18; W1 = w.hW1 + s*NH; b1v = w.hb1 + s*NH; W2 = w.hW2 + s*NH; b2v = w.hb2[s]; }
    tg1[idx] = fcn6(x, W1, b1v, W2, b2v);
}

// --- K2: 2-D delta table via 1-D LDS lerps; chain = 54 * (ds_read + lerp) ---
__global__ __launch_bounds__(256) void LHI_build_2d(
        const float* __restrict__ tg1, __half2* __restrict__ tg2) {
    __shared__ float t1[NF * N1];   // 68 KB
    for (int n = threadIdx.x; n < NF * N1; n += 256) t1[n] = tg1[n];
    __syncthreads();

    const int n = blockIdx.x * 256 + threadIdx.x;
    if (n >= GN * GN) return;
    const int i = n % GN, j = n / GN;
    const float p0 = fmaf((float)i, DLT, ORIG);
    const float q0 = fmaf((float)j, DLT, ORIG);
    float p = p0, q = q0;

    auto lut = [&](int f, float x) -> float {
        float u = fmaf(x, INV1, OFF1);
        u = fminf(fmaxf(u, 0.0f), 510.99f);
        const float fu = floorf(u);
        const int base = f * N1 + (int)fu;
        const float a = t1[base], b = t1[base + 1];
        return fmaf(u - fu, b - a, a);
    };
    const float Hs = 0.1f, hi = Hs / NS;
    p = fmaf(lut(0, q), -0.5f * Hs, p);
    q = fmaf(lut(1, p),         Hs, q);
    p = fmaf(lut(0, q), -0.5f * Hs, p);
    #pragma unroll 1
    for (int s = 0; s < NS; ++s) {
        p = fmaf(lut(2 + s,  q), -0.5f * hi, p);
        q = fmaf(lut(18 + s, p),         hi, q);
        p = fmaf(lut(2 + s,  q), -0.5f * hi, p);
    }
    p = fmaf(lut(0, q),  0.5f * Hs, p);
    q = fmaf(lut(1, p),        -Hs, q);
    p = fmaf(lut(0, q),  0.5f * Hs, p);

    tg2[n] = __floats2half2_rn(p - p0, q - q0);   // |delta| <= ~1
}

__device__ __forceinline__ __half2 h2_from_u32(unsigned u) {
    union { unsigned u; __half2 h; } c; c.u = u; return c.h;
}

// One element through the bilinear-delta fast path (packed fp16 lerp).
__device__ __forceinline__ void lookup2(float& p, float& q,
        const uint2* __restrict__ tab, const P16& w) {
    if (fabsf(p) <= LIM && fabsf(q) <= LIM) {
        const float u  = fmaf(p, INV_D, TAB_OFF);
        const float vv = fmaf(q, INV_D, TAB_OFF);
        const float fu = floorf(u), fv = floorf(vv);
        const int n00 = (int)fv * GN + (int)fu;
        const uint2 r0 = tab[n00];        // (c00, c10)
        const uint2 r1 = tab[n00 + GN];   // (c01, c11)
        const __half2 du2 = __half2half2(__float2half_rn(u - fu));
        const __half2 dv2 = __half2half2(__float2half_rn(vv - fv));
        const __half2 c00 = h2_from_u32(r0.x), c10 = h2_from_u32(r0.y);
        const __half2 c01 = h2_from_u32(r1.x), c11 = h2_from_u32(r1.y);
        const __half2 m0 = __hfma2(du2, __hsub2(c10, c00), c00);
        const __half2 m1 = __hfma2(du2, __hsub2(c11, c01), c01);
        const __half2 m  = __hfma2(dv2, __hsub2(m1, m0), m0);
        const float2 d = __half22float2(m);
        p += d.x; q += d.y;
    } else {
        full_map(p, q, w);   // ~never: execz-skipped when no lane triggers
    }
}

// --- K3: main, persistent grid-stride, float4 I/O, row-pair LDS table ---
__global__ __launch_bounds__(BLK) void LHI_81501299409121_kernel(
        const float4* __restrict__ x4, const __half2* __restrict__ tg,
        P16 w, float4* __restrict__ o4, int nquad, int do_tail,
        const float* __restrict__ x, float* __restrict__ out, int B) {
    __shared__ uint2 tab[GN * GN];   // entry n: (delta[n], delta[n+1])
    const unsigned* tgu = (const unsigned*)tg;
    for (int n = threadIdx.x; n < GN * GN; n += BLK) {
        const int n1 = (n + 1 < GN * GN) ? n + 1 : n;
        tab[n] = make_uint2(tgu[n], tgu[n1]);
    }
    __syncthreads();

    const int tid0   = blockIdx.x * BLK + threadIdx.x;
    const int stride = NBLK * BLK;
    for (int i = tid0; i < nquad; i += stride) {
        float4 v = x4[i];
        lookup2(v.x, v.y, tab, w);
        lookup2(v.z, v.w, tab, w);
        o4[i] = v;
    }
    if (do_tail && tid0 == 0) {
        float p = x[2 * (B - 1)], q = x[2 * (B - 1) + 1];
        full_map(p, q, w);
        out[2 * (B - 1)] = p; out[2 * (B - 1) + 1] = q;
    }
}

// --- fallback if workspace can't hold the tables ---
__global__ __launch_bounds__(256) void LHI_direct_kernel(
        const float* __restrict__ x, P16 w, float* __restrict__ out, int B) {
    const int idx = blockIdx.x * 256 + threadIdx.x;
    if (idx >= B) return;
    float2 v = ((const float2*)x)[idx];
    float p = v.x, q = v.y;
    full_map(p, q, w);
    ((float2*)out)[idx] = make_float2(p, q);
}

extern "C" void kernel_launch(void* const* d_in, const int* in_sizes, int n_in,
                              void* d_out, int out_size, void* d_ws, size_t ws_size,
                              hipStream_t stream) {
    const int B = in_sizes[0] / 2;   // x is [B,2]
    P16 w;
    w.vW1  = (const float*)d_in[1];  w.vb1  = (const float*)d_in[2];
    w.vW2  = (const float*)d_in[3];  w.vb2  = (const float*)d_in[4];
    w.hW1  = (const float*)d_in[5];  w.hb1  = (const float*)d_in[6];
    w.hW2  = (const float*)d_in[7];  w.hb2  = (const float*)d_in[8];
    w.pvW1 = (const float*)d_in[9];  w.pvb1 = (const float*)d_in[10];
    w.pvW2 = (const float*)d_in[11]; w.pvb2 = (const float*)d_in[12];
    w.phW1 = (const float*)d_in[13]; w.phb1 = (const float*)d_in[14];
    w.phW2 = (const float*)d_in[15]; w.phb2 = (const float*)d_in[16];
    const float* x = (const float*)d_in[0];
    float* out = (float*)d_out;

    const size_t sz_1d = (size_t)NF * N1 * sizeof(float);       // 69632 B
    const size_t sz_2d = (size_t)GN * GN * sizeof(__half2);     // 37636 B
    if (ws_size >= sz_1d + sz_2d) {
        float*   tg1 = (float*)d_ws;
        __half2* tg2 = (__half2*)((char*)d_ws + sz_1d);
        LHI_build_1d<<<(NF * N1) / 256, 256, 0, stream>>>(tg1, w);
        LHI_build_2d<<<(GN * GN + 255) / 256, 256, 0, stream>>>(tg1, tg2);
        const int nquad = B >> 1;
        const int do_tail = B & 1;
        LHI_81501299409121_kernel<<<NBLK, BLK, 0, stream>>>(
            (const float4*)x, tg2, w, (float4*)out, nquad, do_tail, x, out, B);
    } else {
        LHI_direct_kernel<<<(B + 255) / 256, 256, 0, stream>>>(x, w, out, B);
    }
}